// Round 15
// baseline (423.470 us; speedup 1.0000x reference)
//
#include <hip/hip_runtime.h>
#include <stdint.h>

#define N_NODES 100000
#define N_EDGES 500000
#define D 128
#define NTILES 6250     // N_NODES / 16
#define NPART 8         // one partition per XCD
#define PART_SZ 12500   // N_NODES / NPART (exact)
#define FCHUNKS 32      // fallback fill: chunks per partition group
#define FCH_EDGES 15625 // N_EDGES / FCHUNKS (exact)
#define SBLK 49         // scan blocks: ceil(100000 / 2048)
#define PREP_BLKS 32    // prep_w blocks inside kernel 1
#define ZERO_BLKS 25    // zeroing blocks inside kernel 1
#define CNT_BLKS 2048   // standalone count blocks (compact fallback path)
#define CAP 72          // capacity-CSR slots per node (P(deg>=72) ~ 8e-10)
#define PAIR_CAP 524288 // pair-region capacity per partition (expect ~375K)
#define BIN_BLKS 512
#define BIN_EPB 2944    // edges per bin block; NOT mult of 256 -> clamp f1!
#define EDGES_TOTAL 1500000
#define FILLP_BLKS 768  // 96 blocks per partition

typedef __bf16 bf16x8 __attribute__((ext_vector_type(8)));
typedef float f32x4 __attribute__((ext_vector_type(4)));

__device__ __forceinline__ unsigned short f2bf(float f) {
    union { float f; unsigned u; } v; v.f = f;
    unsigned u = v.u;
    u += 0x7fffu + ((u >> 16) & 1u);   // round-to-nearest-even
    return (unsigned short)(u >> 16);
}

__device__ __forceinline__ float asf(unsigned u) {
    union { unsigned u; float f; } x; x.u = u; return x.f;
}

// ---------------------------------------------------------------------------
// Kernel 1: blocks [0,32) shuffle weights into MFMA B-fragment order;
// blocks [32, 32+25) zero the padded counters; block 32 also zeros gcnt.
__global__ __launch_bounds__(256) void prep_zero_k(const float* __restrict__ W0,
                                                   const float* __restrict__ W,
                                                   unsigned short* __restrict__ fw,
                                                   uint4* __restrict__ counts_v,
                                                   int* __restrict__ gcnt) {
    const int bid = blockIdx.x;
    if (bid < PREP_BLKS) {
        const int gid = bid * 256 + threadIdx.x;          // 0..8191
        const int l = gid & 63;
        const int s = (gid >> 6) & 3;
        const int n = (gid >> 8) & 7;
        const int m = gid >> 11;                          // 0..3
        const float* src = (m == 0) ? W0 : (W + (m - 1) * D * D);
        const int colw = n * 16 + (l & 15);
        const int k0 = s * 32 + ((l >> 4) << 3);
        unsigned short v[8];
#pragma unroll
        for (int j = 0; j < 8; ++j) v[j] = f2bf(src[(k0 + j) * D + colw]);
        uint4 o;
        o.x = v[0] | ((unsigned)v[1] << 16);
        o.y = v[2] | ((unsigned)v[3] << 16);
        o.z = v[4] | ((unsigned)v[5] << 16);
        o.w = v[6] | ((unsigned)v[7] << 16);
        reinterpret_cast<uint4*>(fw)[gid] = o;
    } else {
        if (bid == PREP_BLKS && threadIdx.x < NPART && gcnt) gcnt[threadIdx.x] = 0;
        const uint4 z = {0u, 0u, 0u, 0u};
        const int stride = ZERO_BLKS * 256;
        for (int i = (bid - PREP_BLKS) * 256 + threadIdx.x; i < N_NODES; i += stride)
            counts_v[i] = z;
    }
}

// ---------------------------------------------------------------------------
// Phase 1: bin the 3M directed entries (dst, src + r*N_NODES) into 8 per-XCD
// pair regions via LDS staging. One pass over the edge list. Flush per
// 256-edge round: one global bump atomic per bucket + coalesced 8B writes.
// BUGFIX vs R13: clamp the per-block edge range to f1 = min(f0+BIN_EPB, TOTAL)
// -- BIN_EPB is not a multiple of 256, so the last round MUST NOT overstep
// into the next block's range (was duplicating 128 edges per boundary).
__global__ __launch_bounds__(256) void bin_k(const int* __restrict__ ea,
                                             const int* __restrict__ eb,
                                             uint2* __restrict__ pairs,
                                             int* __restrict__ gcnt) {
    __shared__ uint2 lbuf[NPART][512];
    __shared__ int lcnt[NPART];
    __shared__ int gbase_s[NPART];
    const int tid = threadIdx.x;
    if (tid < NPART) lcnt[tid] = 0;
    __syncthreads();
    const int f0 = blockIdx.x * BIN_EPB;
    int f1 = f0 + BIN_EPB;
    if (f1 > EDGES_TOTAL) f1 = EDGES_TOTAL;
    for (int base = f0; base < f1; base += 256) {
        const int f = base + tid;
        if (f < f1) {
            const int r = f / N_EDGES;            // 0..2 (magic-mul)
            const int e = f - r * N_EDGES;
            const int a = ea[(size_t)r * N_EDGES + e];
            const int b = eb[(size_t)r * N_EDGES + e];
            const int renc = r * N_NODES;
            // entry 1: dst=a, src=b+renc
            int q = a / PART_SZ;
            int slot = atomicAdd(&lcnt[q], 1);
            lbuf[q][slot] = (uint2){(unsigned)a, (unsigned)(b + renc)};
            // entry 2: dst=b, src=a+renc
            q = b / PART_SZ;
            slot = atomicAdd(&lcnt[q], 1);
            lbuf[q][slot] = (uint2){(unsigned)b, (unsigned)(a + renc)};
        }
        __syncthreads();
        if (tid < NPART) gbase_s[tid] = atomicAdd(&gcnt[tid], lcnt[tid]);
        __syncthreads();
#pragma unroll
        for (int q = 0; q < NPART; ++q) {
            const int c = lcnt[q];
            const int gb = gbase_s[q];
            uint2* dstp = pairs + (size_t)q * PAIR_CAP;
            for (int i = tid; i < c; i += 256) {
                const int pos = gb + i;
                if (pos < PAIR_CAP) dstp[pos] = lbuf[q][i];
            }
        }
        __syncthreads();
        if (tid < NPART) lcnt[tid] = 0;
        __syncthreads();
    }
}

// ---------------------------------------------------------------------------
// Phase 2: dense capacity-CSR fill. Each partition's blocks (p = bid & 7 ->
// XCD p) read ONLY their own pair region, coalesced, once. Slot = atomicAdd
// on the node's padded counter; store at dst*CAP + slot.
__global__ __launch_bounds__(256) void fillp_k(const uint2* __restrict__ pairs,
                                               const int* __restrict__ gcnt,
                                               int* __restrict__ counts_p,
                                               int* __restrict__ eidx_cap) {
    const int p = blockIdx.x & (NPART - 1);
    const int sub = blockIdx.x >> 3;          // 0..95
    int cnt = gcnt[p];
    if (cnt > PAIR_CAP) cnt = PAIR_CAP;
    const uint2* src = pairs + (size_t)p * PAIR_CAP;
    const int stride = (FILLP_BLKS / NPART) * 256;
    for (int i = sub * 256 + threadIdx.x; i < cnt; i += stride) {
        const uint2 pr = src[i];
        const int dst = (int)pr.x;
        const int old = atomicAdd(&counts_p[dst << 2], 1);
        if (old < CAP) eidx_cap[(size_t)dst * CAP + old] = (int)pr.y;
    }
}

// ---------------------------------------------------------------------------
// FALLBACK path kernels (compact CSR; only used if ws is too small).
__global__ __launch_bounds__(256) void count_k(const int* __restrict__ ea,
                                               const int* __restrict__ eb,
                                               int* __restrict__ counts_p) {
    const int stride = CNT_BLKS * 256;
    for (int e = blockIdx.x * 256 + threadIdx.x; e < 3 * N_EDGES; e += stride) {
        atomicAdd(&counts_p[ea[e] << 2], 1);
        atomicAdd(&counts_p[eb[e] << 2], 1);
    }
}

__global__ __launch_bounds__(256) void scan1_k(const int* __restrict__ counts_p,
                                               int* __restrict__ offs,
                                               int* __restrict__ bsum) {
    __shared__ int sums[256];
    const int t = threadIdx.x;
    const int base = blockIdx.x * 2048 + t * 8;
    int v[8];
    int s = 0;
#pragma unroll
    for (int j = 0; j < 8; ++j) {
        const int idx = base + j;
        v[j] = (idx < N_NODES) ? counts_p[idx << 2] : 0;
        s += v[j];
    }
    sums[t] = s;
    __syncthreads();
    for (int off = 1; off < 256; off <<= 1) {
        const int tv = (t >= off) ? sums[t - off] : 0;
        __syncthreads();
        sums[t] += tv;
        __syncthreads();
    }
    int excl = sums[t] - s;
#pragma unroll
    for (int j = 0; j < 8; ++j) {
        const int idx = base + j;
        if (idx < N_NODES) offs[idx] = excl;
        excl += v[j];
    }
    if (t == 255) bsum[blockIdx.x] = sums[255];
}

__global__ __launch_bounds__(64) void scan2_k(const int* __restrict__ bsum,
                                              int* __restrict__ bpre,
                                              int* __restrict__ offs) {
    __shared__ int s[64];
    const int t = threadIdx.x;
    const int v = (t < SBLK) ? bsum[t] : 0;
    s[t] = v;
    __syncthreads();
    for (int off = 1; off < 64; off <<= 1) {
        const int tv = (t >= off) ? s[t - off] : 0;
        __syncthreads();
        s[t] += tv;
        __syncthreads();
    }
    bpre[t] = s[t] - v;
    if (t == 63) offs[N_NODES] = s[63];
}

__global__ __launch_bounds__(256) void scan3_k(int* __restrict__ offs,
                                               const int* __restrict__ bpre) {
    const int add = bpre[blockIdx.x];
    const int base = blockIdx.x * 2048 + threadIdx.x * 8;
#pragma unroll
    for (int j = 0; j < 8; ++j) {
        const int idx = base + j;
        if (idx < N_NODES) offs[idx] += add;
    }
}

__global__ __launch_bounds__(256) void fill_k(const int* __restrict__ ea,
                                              const int* __restrict__ eb,
                                              const int* __restrict__ offs,
                                              int* __restrict__ counts_p,
                                              int* __restrict__ eidx) {
    const int bid = blockIdx.x;
    const int p = bid & (NPART - 1);
    const int j = bid >> 3;
    const int r = j >> 5;
    const int chunk = j & 31;
    const int lo = p * PART_SZ;
    const int e0 = chunk * FCH_EDGES;
    const int e1 = e0 + FCH_EDGES;
    const int* pa = ea + (size_t)r * N_EDGES;
    const int* pb = eb + (size_t)r * N_EDGES;
    const int roff = r * N_NODES;
    for (int e = e0 + threadIdx.x; e < e1; e += 256) {
        const int a = pa[e];
        const int b = pb[e];
        if ((unsigned)(a - lo) < (unsigned)PART_SZ) {
            const int old = atomicSub(&counts_p[a << 2], 1);
            eidx[offs[a] + old - 1] = b + roff;
        }
        if ((unsigned)(b - lo) < (unsigned)PART_SZ) {
            const int old = atomicSub(&counts_p[b << 2], 1);
            eidx[offs[b] + old - 1] = a + roff;
        }
    }
}

// ---------------------------------------------------------------------------
// 4-matrix GEMM, standalone (NEVER fused -- R5/R9/R10 lesson): reads X once,
// writes out = X@W0 (f32) and Yb[r] = bf16(X@W[r]) r=0..2.
__global__ __launch_bounds__(256) void gemm4_k(const float* __restrict__ X,
                                               const unsigned short* __restrict__ fw,
                                               float* __restrict__ out,
                                               unsigned short* __restrict__ Yb) {
    const int wid = threadIdx.x >> 6;
    const int l = threadIdx.x & 63;
    const int t = blockIdx.x * 4 + wid;
    if (t >= NTILES) return;
    const float4* xr = reinterpret_cast<const float4*>(
        X + (size_t)(t * 16 + (l & 15)) * D + ((l >> 4) << 3));
    bf16x8 a[4];
#pragma unroll
    for (int s = 0; s < 4; ++s) {
        const float4 f0 = xr[s * 8];
        const float4 f1 = xr[s * 8 + 1];
        union { uint4 u; bf16x8 h; } pk;
        pk.u.x = f2bf(f0.x) | ((unsigned)f2bf(f0.y) << 16);
        pk.u.y = f2bf(f0.z) | ((unsigned)f2bf(f0.w) << 16);
        pk.u.z = f2bf(f1.x) | ((unsigned)f2bf(f1.y) << 16);
        pk.u.w = f2bf(f1.z) | ((unsigned)f2bf(f1.w) << 16);
        a[s] = pk.h;
    }
    const bf16x8* bw = reinterpret_cast<const bf16x8*>(fw) + l;
    const int rbase = t * 16 + ((l >> 4) << 2);   // C/D: col=lane&15, row=(lane>>4)*4+q
    const int colb = l & 15;
#pragma unroll
    for (int m = 0; m < 4; ++m) {
        f32x4 acc[8];
#pragma unroll
        for (int n = 0; n < 8; ++n) acc[n] = (f32x4){0.f, 0.f, 0.f, 0.f};
#pragma unroll
        for (int n = 0; n < 8; ++n) {
#pragma unroll
            for (int s = 0; s < 4; ++s)
                acc[n] = __builtin_amdgcn_mfma_f32_16x16x32_bf16(
                    a[s], bw[m * 2048 + (n * 4 + s) * 64], acc[n], 0, 0, 0);
        }
        if (m == 0) {
#pragma unroll
            for (int n = 0; n < 8; ++n)
#pragma unroll
                for (int q = 0; q < 4; ++q)
                    out[(size_t)(rbase + q) * D + n * 16 + colb] = acc[n][q];
        } else {
            unsigned short* yo = Yb + (size_t)(m - 1) * N_NODES * D;
#pragma unroll
            for (int n = 0; n < 8; ++n)
#pragma unroll
                for (int q = 0; q < 4; ++q)
                    yo[(size_t)(rbase + q) * D + n * 16 + colb] = f2bf(acc[n][q]);
        }
    }
}

// ---------------------------------------------------------------------------
// Paired-row pull gather. cap_mode=1: neighbors at [n*CAP, n*CAP+min(cnt,CAP));
// else [offs[n], offs[n+1]).
__global__ __launch_bounds__(256) void gather_k(const unsigned* __restrict__ Yu,
                                                const int* __restrict__ offs_or_cnt,
                                                const int* __restrict__ eidx,
                                                float* __restrict__ out,
                                                const float* __restrict__ norms,
                                                const float* __restrict__ bias,
                                                int cap_mode) {
    const int wid = threadIdx.x >> 6;
    const int l = threadIdx.x & 63;
    const int n = blockIdx.x * 4 + wid;
    if (n >= N_NODES) return;
    int s0, s1;
    if (cap_mode) {
        s0 = n * CAP;
        int len = offs_or_cnt[n << 2];
        if (len > CAP) len = CAP;
        s1 = s0 + len;
    } else {
        s0 = offs_or_cnt[n];
        s1 = offs_or_cnt[n + 1];
    }
    const int rs = l >> 5;              // which row of the pair
    const int sub = l & 31;             // uint2 index within row
    const uint2* Y2 = reinterpret_cast<const uint2*>(Yu);   // row = 32 uint2
    float a0 = 0.f, a1 = 0.f, a2 = 0.f, a3 = 0.f;
    int i = s0;
    for (; i + 16 <= s1; i += 16) {     // 8 pairs = 16 rows
        int c[8];
        uint2 v[8];
#pragma unroll
        for (int k = 0; k < 8; ++k) c[k] = eidx[i + 2 * k + rs];
#pragma unroll
        for (int k = 0; k < 8; ++k) v[k] = Y2[(size_t)c[k] * 32 + sub];
#pragma unroll
        for (int k = 0; k < 8; ++k) {
            a0 += asf(v[k].x << 16); a1 += asf(v[k].x & 0xffff0000u);
            a2 += asf(v[k].y << 16); a3 += asf(v[k].y & 0xffff0000u);
        }
    }
    for (; i + 4 <= s1; i += 4) {       // 2 pairs
        const int c0 = eidx[i + rs];
        const int c1 = eidx[i + 2 + rs];
        const uint2 v0 = Y2[(size_t)c0 * 32 + sub];
        const uint2 v1 = Y2[(size_t)c1 * 32 + sub];
        a0 += asf(v0.x << 16); a1 += asf(v0.x & 0xffff0000u);
        a2 += asf(v0.y << 16); a3 += asf(v0.y & 0xffff0000u);
        a0 += asf(v1.x << 16); a1 += asf(v1.x & 0xffff0000u);
        a2 += asf(v1.y << 16); a3 += asf(v1.y & 0xffff0000u);
    }
    for (; i < s1; i += 2) {            // tail pair (odd-degree: hi half idles)
        const int jj = i + rs;
        if (jj < s1) {
            const int c = eidx[jj];
            const uint2 v = Y2[(size_t)c * 32 + sub];
            a0 += asf(v.x << 16); a1 += asf(v.x & 0xffff0000u);
            a2 += asf(v.y << 16); a3 += asf(v.y & 0xffff0000u);
        }
    }
    a0 += __shfl_xor(a0, 32);
    a1 += __shfl_xor(a1, 32);
    a2 += __shfl_xor(a2, 32);
    a3 += __shfl_xor(a3, 32);
    if (rs == 0) {
        float4* op = reinterpret_cast<float4*>(out + (size_t)n * D) + sub;
        const float4 cur = *op;
        const float nm = norms[n];
        const float4 bb = reinterpret_cast<const float4*>(bias)[sub];
        float4 res;
        res.x = (cur.x + a0) * nm + bb.x;
        res.y = (cur.y + a1) * nm + bb.y;
        res.z = (cur.z + a2) * nm + bb.z;
        res.w = (cur.w + a3) * nm + bb.w;
        *op = res;
    }
}

// ---------------------------------------------------------------------------
extern "C" void kernel_launch(void* const* d_in, const int* in_sizes, int n_in,
                              void* d_out, int out_size, void* d_ws, size_t ws_size,
                              hipStream_t stream) {
    const float* X      = (const float*)d_in[0];
    const int*   ref_a  = (const int*)d_in[1];
    const int*   ref_b  = (const int*)d_in[2];
    const float* norms  = (const float*)d_in[3];
    const float* W0     = (const float*)d_in[4];
    const float* W      = (const float*)d_in[5];
    const float* bias   = (const float*)d_in[6];
    float* out = (float*)d_out;

    char* ws = (char*)d_ws;
    const size_t NEED_CAP = 107331072ULL;   // 3xYb + eidx_cap + fw + counts

    if (ws_size >= NEED_CAP) {
        // --- two-phase capacity-CSR path ---
        unsigned short* Yb = (unsigned short*)ws;                 //  76,800,000
        // pairs buffer ALIASES Yb (dead before gemm4 writes Yb):
        uint2* pairs       = (uint2*)ws;                          //  33,554,432
        int* gcnt          = (int*)(ws + 33554432);               //          32
        int* eidx_cap      = (int*)(ws + 76800000);               //  28,800,000
        unsigned short* fw = (unsigned short*)(ws + 105600000);   //     131,072
        int* counts_p      = (int*)(ws + 105731072);              //   1,600,000

        prep_zero_k<<<PREP_BLKS + ZERO_BLKS, 256, 0, stream>>>(
            W0, W, fw, reinterpret_cast<uint4*>(counts_p), gcnt);
        // phase 1: one-pass binning into per-XCD pair regions
        bin_k<<<BIN_BLKS, 256, 0, stream>>>(ref_a, ref_b, pairs, gcnt);
        // phase 2: dense per-XCD fill
        fillp_k<<<FILLP_BLKS, 256, 0, stream>>>(pairs, gcnt, counts_p, eidx_cap);
        // GEMM overwrites the pairs region with Yb
        gemm4_k<<<(NTILES + 3) / 4, 256, 0, stream>>>(X, fw, out, Yb);
        gather_k<<<(N_NODES + 3) / 4, 256, 0, stream>>>(
            (const unsigned*)Yb, counts_p, eidx_cap, out, norms, bias, 1);
    } else {
        // --- compact-CSR fallback (count + scan + fill) ---
        unsigned short* Yb = (unsigned short*)ws;                 //  76,800,000
        int* eidx          = (int*)(ws + 76800000);               //  12,000,000
        unsigned short* fw = (unsigned short*)(ws + 88800000);    //     131,072
        int* offs          = (int*)(ws + 88931072);               //     400,016
        int* bsum          = (int*)(ws + 89331088);               //         256
        int* bpre          = (int*)(ws + 89331344);               //         272
        int* counts_p      = (int*)(ws + 89331616);               //   1,600,000

        prep_zero_k<<<PREP_BLKS + ZERO_BLKS, 256, 0, stream>>>(
            W0, W, fw, reinterpret_cast<uint4*>(counts_p), nullptr);
        count_k<<<CNT_BLKS, 256, 0, stream>>>(ref_a, ref_b, counts_p);
        scan1_k<<<SBLK, 256, 0, stream>>>(counts_p, offs, bsum);
        scan2_k<<<1, 64, 0, stream>>>(bsum, bpre, offs);
        scan3_k<<<SBLK, 256, 0, stream>>>(offs, bpre);
        fill_k<<<FCHUNKS * NPART * 3, 256, 0, stream>>>(
            ref_a, ref_b, offs, counts_p, eidx);
        gemm4_k<<<(NTILES + 3) / 4, 256, 0, stream>>>(X, fw, out, Yb);
        gather_k<<<(N_NODES + 3) / 4, 256, 0, stream>>>(
            (const unsigned*)Yb, offs, eidx, out, norms, bias, 0);
    }
}

// Round 16
// 298.871 us; speedup vs baseline: 1.4169x; 1.4169x over previous
//
#include <hip/hip_runtime.h>
#include <stdint.h>

#define N_NODES 100000
#define N_EDGES 500000
#define D 128
#define NTILES 6250     // N_NODES / 16
#define NPART 8         // one partition per XCD
#define PART_SZ 12500   // N_NODES / NPART (exact)
#define FCHUNKS 32      // fill: edge-list chunks per partition group
#define FCH_EDGES 15625 // N_EDGES / FCHUNKS (exact)
#define SBLK 49         // scan blocks: ceil(100000 / 2048)
#define PREP_BLKS 32    // prep_w blocks inside kernel 1
#define ZERO_BLKS 25    // zeroing blocks inside kernel 1
#define CNT_BLKS 2048   // standalone count blocks (compact fallback path)
#define CAP 72          // capacity-CSR slots per node (P(deg>=72) ~ 8e-10)
// counters: 16B stride per node (index = node << 2)

typedef __bf16 bf16x8 __attribute__((ext_vector_type(8)));
typedef float f32x4 __attribute__((ext_vector_type(4)));

__device__ __forceinline__ unsigned short f2bf(float f) {
    union { float f; unsigned u; } v; v.f = f;
    unsigned u = v.u;
    u += 0x7fffu + ((u >> 16) & 1u);   // round-to-nearest-even
    return (unsigned short)(u >> 16);
}

__device__ __forceinline__ float asf(unsigned u) {
    union { unsigned u; float f; } x; x.u = u; return x.f;
}

// ---------------------------------------------------------------------------
// Kernel 1: blocks [0,32) shuffle weights into MFMA B-fragment order;
// blocks [32, 32+25) zero the padded counters.
__global__ __launch_bounds__(256) void prep_zero_k(const float* __restrict__ W0,
                                                   const float* __restrict__ W,
                                                   unsigned short* __restrict__ fw,
                                                   uint4* __restrict__ counts_v) {
    const int bid = blockIdx.x;
    if (bid < PREP_BLKS) {
        const int gid = bid * 256 + threadIdx.x;          // 0..8191
        const int l = gid & 63;
        const int s = (gid >> 6) & 3;
        const int n = (gid >> 8) & 7;
        const int m = gid >> 11;                          // 0..3
        const float* src = (m == 0) ? W0 : (W + (m - 1) * D * D);
        const int colw = n * 16 + (l & 15);
        const int k0 = s * 32 + ((l >> 4) << 3);
        unsigned short v[8];
#pragma unroll
        for (int j = 0; j < 8; ++j) v[j] = f2bf(src[(k0 + j) * D + colw]);
        uint4 o;
        o.x = v[0] | ((unsigned)v[1] << 16);
        o.y = v[2] | ((unsigned)v[3] << 16);
        o.z = v[4] | ((unsigned)v[5] << 16);
        o.w = v[6] | ((unsigned)v[7] << 16);
        reinterpret_cast<uint4*>(fw)[gid] = o;
    } else {
        const uint4 z = {0u, 0u, 0u, 0u};
        const int stride = ZERO_BLKS * 256;
        for (int i = (bid - PREP_BLKS) * 256 + threadIdx.x; i < N_NODES; i += stride)
            counts_v[i] = z;
    }
}

// ---------------------------------------------------------------------------
// Capacity-CSR build (R11 proven config: 768 blocks, XCD-partitioned, plain
// loads -- NT loads REGRESSED, R12). Slot = atomicAdd on padded counter;
// store at n*CAP + slot. src encodes relation as src + r*N_NODES.
__global__ __launch_bounds__(256) void fillcap_k(const int* __restrict__ ea,
                                                 const int* __restrict__ eb,
                                                 int* __restrict__ counts_p,
                                                 int* __restrict__ eidx_cap) {
    const int bid = blockIdx.x;
    const int p = bid & (NPART - 1);
    const int j = bid >> 3;            // 0..95
    const int r = j >> 5;              // relation 0..2
    const int chunk = j & 31;
    const int lo = p * PART_SZ;
    const int e0 = chunk * FCH_EDGES;
    const int e1 = e0 + FCH_EDGES;
    const int* pa = ea + (size_t)r * N_EDGES;
    const int* pb = eb + (size_t)r * N_EDGES;
    const int roff = r * N_NODES;
    for (int e = e0 + threadIdx.x; e < e1; e += 256) {
        const int a = pa[e];
        const int b = pb[e];
        if ((unsigned)(a - lo) < (unsigned)PART_SZ) {
            const int old = atomicAdd(&counts_p[a << 2], 1);
            if (old < CAP) eidx_cap[a * CAP + old] = b + roff;
        }
        if ((unsigned)(b - lo) < (unsigned)PART_SZ) {
            const int old = atomicAdd(&counts_p[b << 2], 1);
            if (old < CAP) eidx_cap[b * CAP + old] = a + roff;
        }
    }
}

// ---------------------------------------------------------------------------
// FALLBACK path kernels (compact CSR; only used if ws is too small).
__global__ __launch_bounds__(256) void count_k(const int* __restrict__ ea,
                                               const int* __restrict__ eb,
                                               int* __restrict__ counts_p) {
    const int stride = CNT_BLKS * 256;
    for (int e = blockIdx.x * 256 + threadIdx.x; e < 3 * N_EDGES; e += stride) {
        atomicAdd(&counts_p[ea[e] << 2], 1);
        atomicAdd(&counts_p[eb[e] << 2], 1);
    }
}

__global__ __launch_bounds__(256) void scan1_k(const int* __restrict__ counts_p,
                                               int* __restrict__ offs,
                                               int* __restrict__ bsum) {
    __shared__ int sums[256];
    const int t = threadIdx.x;
    const int base = blockIdx.x * 2048 + t * 8;
    int v[8];
    int s = 0;
#pragma unroll
    for (int j = 0; j < 8; ++j) {
        const int idx = base + j;
        v[j] = (idx < N_NODES) ? counts_p[idx << 2] : 0;
        s += v[j];
    }
    sums[t] = s;
    __syncthreads();
    for (int off = 1; off < 256; off <<= 1) {
        const int tv = (t >= off) ? sums[t - off] : 0;
        __syncthreads();
        sums[t] += tv;
        __syncthreads();
    }
    int excl = sums[t] - s;
#pragma unroll
    for (int j = 0; j < 8; ++j) {
        const int idx = base + j;
        if (idx < N_NODES) offs[idx] = excl;
        excl += v[j];
    }
    if (t == 255) bsum[blockIdx.x] = sums[255];
}

__global__ __launch_bounds__(64) void scan2_k(const int* __restrict__ bsum,
                                              int* __restrict__ bpre,
                                              int* __restrict__ offs) {
    __shared__ int s[64];
    const int t = threadIdx.x;
    const int v = (t < SBLK) ? bsum[t] : 0;
    s[t] = v;
    __syncthreads();
    for (int off = 1; off < 64; off <<= 1) {
        const int tv = (t >= off) ? s[t - off] : 0;
        __syncthreads();
        s[t] += tv;
        __syncthreads();
    }
    bpre[t] = s[t] - v;
    if (t == 63) offs[N_NODES] = s[63];
}

__global__ __launch_bounds__(256) void scan3_k(int* __restrict__ offs,
                                               const int* __restrict__ bpre) {
    const int add = bpre[blockIdx.x];
    const int base = blockIdx.x * 2048 + threadIdx.x * 8;
#pragma unroll
    for (int j = 0; j < 8; ++j) {
        const int idx = base + j;
        if (idx < N_NODES) offs[idx] += add;
    }
}

__global__ __launch_bounds__(256) void fill_k(const int* __restrict__ ea,
                                              const int* __restrict__ eb,
                                              const int* __restrict__ offs,
                                              int* __restrict__ counts_p,
                                              int* __restrict__ eidx) {
    const int bid = blockIdx.x;
    const int p = bid & (NPART - 1);
    const int j = bid >> 3;
    const int r = j >> 5;
    const int chunk = j & 31;
    const int lo = p * PART_SZ;
    const int e0 = chunk * FCH_EDGES;
    const int e1 = e0 + FCH_EDGES;
    const int* pa = ea + (size_t)r * N_EDGES;
    const int* pb = eb + (size_t)r * N_EDGES;
    const int roff = r * N_NODES;
    for (int e = e0 + threadIdx.x; e < e1; e += 256) {
        const int a = pa[e];
        const int b = pb[e];
        if ((unsigned)(a - lo) < (unsigned)PART_SZ) {
            const int old = atomicSub(&counts_p[a << 2], 1);
            eidx[offs[a] + old - 1] = b + roff;
        }
        if ((unsigned)(b - lo) < (unsigned)PART_SZ) {
            const int old = atomicSub(&counts_p[b << 2], 1);
            eidx[offs[b] + old - 1] = a + roff;
        }
    }
}

// ---------------------------------------------------------------------------
// 4-matrix GEMM, standalone (NEVER fused -- R5/R9/R10 lesson). Reads X once.
// self_bf16=1: W0 product -> Yb[3] (bf16); out untouched (gather writes it
// once). self_bf16=0: W0 product -> out (f32).
__global__ __launch_bounds__(256) void gemm4_k(const float* __restrict__ X,
                                               const unsigned short* __restrict__ fw,
                                               float* __restrict__ out,
                                               unsigned short* __restrict__ Yb,
                                               int self_bf16) {
    const int wid = threadIdx.x >> 6;
    const int l = threadIdx.x & 63;
    const int t = blockIdx.x * 4 + wid;
    if (t >= NTILES) return;
    const float4* xr = reinterpret_cast<const float4*>(
        X + (size_t)(t * 16 + (l & 15)) * D + ((l >> 4) << 3));
    bf16x8 a[4];
#pragma unroll
    for (int s = 0; s < 4; ++s) {
        const float4 f0 = xr[s * 8];
        const float4 f1 = xr[s * 8 + 1];
        union { uint4 u; bf16x8 h; } pk;
        pk.u.x = f2bf(f0.x) | ((unsigned)f2bf(f0.y) << 16);
        pk.u.y = f2bf(f0.z) | ((unsigned)f2bf(f0.w) << 16);
        pk.u.z = f2bf(f1.x) | ((unsigned)f2bf(f1.y) << 16);
        pk.u.w = f2bf(f1.z) | ((unsigned)f2bf(f1.w) << 16);
        a[s] = pk.h;
    }
    const bf16x8* bw = reinterpret_cast<const bf16x8*>(fw) + l;
    const int rbase = t * 16 + ((l >> 4) << 2);   // C/D: col=lane&15, row=(lane>>4)*4+q
    const int colb = l & 15;
#pragma unroll
    for (int m = 0; m < 4; ++m) {
        f32x4 acc[8];
#pragma unroll
        for (int n = 0; n < 8; ++n) acc[n] = (f32x4){0.f, 0.f, 0.f, 0.f};
#pragma unroll
        for (int n = 0; n < 8; ++n) {
#pragma unroll
            for (int s = 0; s < 4; ++s)
                acc[n] = __builtin_amdgcn_mfma_f32_16x16x32_bf16(
                    a[s], bw[m * 2048 + (n * 4 + s) * 64], acc[n], 0, 0, 0);
        }
        if (m == 0 && !self_bf16) {
#pragma unroll
            for (int n = 0; n < 8; ++n)
#pragma unroll
                for (int q = 0; q < 4; ++q)
                    out[(size_t)(rbase + q) * D + n * 16 + colb] = acc[n][q];
        } else {
            const int slot = (m == 0) ? 3 : (m - 1);
            unsigned short* yo = Yb + (size_t)slot * N_NODES * D;
#pragma unroll
            for (int n = 0; n < 8; ++n)
#pragma unroll
                for (int q = 0; q < 4; ++q)
                    yo[(size_t)(rbase + q) * D + n * 16 + colb] = f2bf(acc[n][q]);
        }
    }
}

// ---------------------------------------------------------------------------
// Paired-row pull gather. cap_mode=1: neighbors at [n*CAP, n*CAP+min(cnt,CAP));
// cap_mode=0: [offs[n], offs[n+1]). self_bf16=1: self term from Yb[3] row n
// (out write-only); else self term read from out (f32).
__global__ __launch_bounds__(256) void gather_k(const unsigned* __restrict__ Yu,
                                                const int* __restrict__ offs_or_cnt,
                                                const int* __restrict__ eidx,
                                                float* __restrict__ out,
                                                const float* __restrict__ norms,
                                                const float* __restrict__ bias,
                                                int cap_mode, int self_bf16) {
    const int wid = threadIdx.x >> 6;
    const int l = threadIdx.x & 63;
    const int n = blockIdx.x * 4 + wid;
    if (n >= N_NODES) return;
    int s0, s1;
    if (cap_mode) {
        s0 = n * CAP;
        int len = offs_or_cnt[n << 2];
        if (len > CAP) len = CAP;
        s1 = s0 + len;
    } else {
        s0 = offs_or_cnt[n];
        s1 = offs_or_cnt[n + 1];
    }
    const int rs = l >> 5;              // which row of the pair
    const int sub = l & 31;             // uint2 index within row
    const uint2* Y2 = reinterpret_cast<const uint2*>(Yu);   // row = 32 uint2
    float a0 = 0.f, a1 = 0.f, a2 = 0.f, a3 = 0.f;
    int i = s0;
    for (; i + 16 <= s1; i += 16) {     // 8 pairs = 16 rows
        int c[8];
        uint2 v[8];
#pragma unroll
        for (int k = 0; k < 8; ++k) c[k] = eidx[i + 2 * k + rs];
#pragma unroll
        for (int k = 0; k < 8; ++k) v[k] = Y2[(size_t)c[k] * 32 + sub];
#pragma unroll
        for (int k = 0; k < 8; ++k) {
            a0 += asf(v[k].x << 16); a1 += asf(v[k].x & 0xffff0000u);
            a2 += asf(v[k].y << 16); a3 += asf(v[k].y & 0xffff0000u);
        }
    }
    for (; i + 4 <= s1; i += 4) {       // 2 pairs
        const int c0 = eidx[i + rs];
        const int c1 = eidx[i + 2 + rs];
        const uint2 v0 = Y2[(size_t)c0 * 32 + sub];
        const uint2 v1 = Y2[(size_t)c1 * 32 + sub];
        a0 += asf(v0.x << 16); a1 += asf(v0.x & 0xffff0000u);
        a2 += asf(v0.y << 16); a3 += asf(v0.y & 0xffff0000u);
        a0 += asf(v1.x << 16); a1 += asf(v1.x & 0xffff0000u);
        a2 += asf(v1.y << 16); a3 += asf(v1.y & 0xffff0000u);
    }
    for (; i < s1; i += 2) {            // tail pair (odd-degree: hi half idles)
        const int jj = i + rs;
        if (jj < s1) {
            const int c = eidx[jj];
            const uint2 v = Y2[(size_t)c * 32 + sub];
            a0 += asf(v.x << 16); a1 += asf(v.x & 0xffff0000u);
            a2 += asf(v.y << 16); a3 += asf(v.y & 0xffff0000u);
        }
    }
    a0 += __shfl_xor(a0, 32);
    a1 += __shfl_xor(a1, 32);
    a2 += __shfl_xor(a2, 32);
    a3 += __shfl_xor(a3, 32);
    if (rs == 0) {
        float4* op = reinterpret_cast<float4*>(out + (size_t)n * D) + sub;
        const float nm = norms[n];
        const float4 bb = reinterpret_cast<const float4*>(bias)[sub];
        float s0v, s1v, s2v, s3v;
        if (self_bf16) {
            const uint2 sv = Y2[((size_t)3 * N_NODES + n) * 32 + sub];
            s0v = asf(sv.x << 16); s1v = asf(sv.x & 0xffff0000u);
            s2v = asf(sv.y << 16); s3v = asf(sv.y & 0xffff0000u);
        } else {
            const float4 cur = *op;
            s0v = cur.x; s1v = cur.y; s2v = cur.z; s3v = cur.w;
        }
        float4 res;
        res.x = (s0v + a0) * nm + bb.x;
        res.y = (s1v + a1) * nm + bb.y;
        res.z = (s2v + a2) * nm + bb.z;
        res.w = (s3v + a3) * nm + bb.w;
        *op = res;
    }
}

// ---------------------------------------------------------------------------
extern "C" void kernel_launch(void* const* d_in, const int* in_sizes, int n_in,
                              void* d_out, int out_size, void* d_ws, size_t ws_size,
                              hipStream_t stream) {
    const float* X      = (const float*)d_in[0];
    const int*   ref_a  = (const int*)d_in[1];
    const int*   ref_b  = (const int*)d_in[2];
    const float* norms  = (const float*)d_in[3];
    const float* W0     = (const float*)d_in[4];
    const float* W      = (const float*)d_in[5];
    const float* bias   = (const float*)d_in[6];
    float* out = (float*)d_out;

    char* ws = (char*)d_ws;
    const size_t NEED_SELF = 132931072ULL;   // 4xYb + eidx_cap + fw + counts
    const size_t NEED_CAP  = 107331072ULL;   // 3xYb + eidx_cap + fw + counts (R11, proven)

    if (ws_size >= NEED_SELF) {
        // --- R11 structure + bf16 self term (out written exactly once) ---
        unsigned short* Yb = (unsigned short*)ws;                 // 102,400,000
        int* eidx_cap      = (int*)(ws + 102400000);              //  28,800,000
        unsigned short* fw = (unsigned short*)(ws + 131200000);   //     131,072
        int* counts_p      = (int*)(ws + 131331072);              //   1,600,000

        prep_zero_k<<<PREP_BLKS + ZERO_BLKS, 256, 0, stream>>>(
            W0, W, fw, reinterpret_cast<uint4*>(counts_p));
        fillcap_k<<<FCHUNKS * NPART * 3, 256, 0, stream>>>(
            ref_a, ref_b, counts_p, eidx_cap);
        gemm4_k<<<(NTILES + 3) / 4, 256, 0, stream>>>(X, fw, out, Yb, 1);
        gather_k<<<(N_NODES + 3) / 4, 256, 0, stream>>>(
            (const unsigned*)Yb, counts_p, eidx_cap, out, norms, bias, 1, 1);
    } else if (ws_size >= NEED_CAP) {
        // --- exact R11 path (proven 322 us) ---
        unsigned short* Yb = (unsigned short*)ws;                 //  76,800,000
        int* eidx_cap      = (int*)(ws + 76800000);               //  28,800,000
        unsigned short* fw = (unsigned short*)(ws + 105600000);   //     131,072
        int* counts_p      = (int*)(ws + 105731072);              //   1,600,000

        prep_zero_k<<<PREP_BLKS + ZERO_BLKS, 256, 0, stream>>>(
            W0, W, fw, reinterpret_cast<uint4*>(counts_p));
        fillcap_k<<<FCHUNKS * NPART * 3, 256, 0, stream>>>(
            ref_a, ref_b, counts_p, eidx_cap);
        gemm4_k<<<(NTILES + 3) / 4, 256, 0, stream>>>(X, fw, out, Yb, 0);
        gather_k<<<(N_NODES + 3) / 4, 256, 0, stream>>>(
            (const unsigned*)Yb, counts_p, eidx_cap, out, norms, bias, 1, 0);
    } else {
        // --- compact-CSR fallback (count + scan + fill) ---
        unsigned short* Yb = (unsigned short*)ws;                 //  76,800,000
        int* eidx          = (int*)(ws + 76800000);               //  12,000,000
        unsigned short* fw = (unsigned short*)(ws + 88800000);    //     131,072
        int* offs          = (int*)(ws + 88931072);               //     400,016
        int* bsum          = (int*)(ws + 89331088);               //         256
        int* bpre          = (int*)(ws + 89331344);               //         272
        int* counts_p      = (int*)(ws + 89331616);               //   1,600,000

        prep_zero_k<<<PREP_BLKS + ZERO_BLKS, 256, 0, stream>>>(
            W0, W, fw, reinterpret_cast<uint4*>(counts_p));
        count_k<<<CNT_BLKS, 256, 0, stream>>>(ref_a, ref_b, counts_p);
        scan1_k<<<SBLK, 256, 0, stream>>>(counts_p, offs, bsum);
        scan2_k<<<1, 64, 0, stream>>>(bsum, bpre, offs);
        scan3_k<<<SBLK, 256, 0, stream>>>(offs, bpre);
        fill_k<<<FCHUNKS * NPART * 3, 256, 0, stream>>>(
            ref_a, ref_b, offs, counts_p, eidx);
        gemm4_k<<<(NTILES + 3) / 4, 256, 0, stream>>>(X, fw, out, Yb, 0);
        gather_k<<<(N_NODES + 3) / 4, 256, 0, stream>>>(
            (const unsigned*)Yb, offs, eidx, out, norms, bias, 0, 0);
    }
}